// Round 20
// baseline (642.680 us; speedup 1.0000x reference)
//
#include <hip/hip_runtime.h>
#include <hip/hip_bf16.h>

#define BATCH 65536
#define DIN   256
#define DHID  512
#define BM    32
#define APAD  264   // 256+8 shorts; rows 16B-aligned
#define HPADW 520   // 512+8 shorts
#define NSTEPS 2    // RK2 (midpoint) x 2 = 4 f-evals

typedef __attribute__((ext_vector_type(8))) short short8;
typedef __attribute__((ext_vector_type(4))) float f32x4;
typedef unsigned long long u64;

__device__ __forceinline__ unsigned short f2bf(float f){
  union { float f; unsigned u; } v; v.f = f;
  unsigned u = v.u;
  unsigned r = (u + 0x7FFFu + ((u >> 16) & 1u)) >> 16;   // RN-even
  return (unsigned short)r;
}
// 4x f32 -> packed 4x bf16 via hardware v_cvt_pk_bf16_f32 (RN-even)
__device__ __forceinline__ u64 pack4bf(float a, float b, float c, float d){
  union { __hip_bfloat162 h2; unsigned u; } lo, hi;
  lo.h2 = __float22bfloat162_rn(make_float2(a, b));
  hi.h2 = __float22bfloat162_rn(make_float2(c, d));
  return (u64)lo.u | ((u64)hi.u << 32);
}
__device__ __forceinline__ float tanh_fast(float x){
  float e = __expf(2.0f * x);
  return 1.0f - 2.0f / (e + 1.0f);
}

// Packed per-wave MFMA fragment order (r10; bytes unchanged, used as the
// A-operand of the swapped mfma — A/B fragment index maps are identical).
__global__ void prep_pack(const float* __restrict__ W1, const float* __restrict__ W2,
                          unsigned short* __restrict__ W1p, unsigned short* __restrict__ W2p){
  int idx = blockIdx.x * blockDim.x + threadIdx.x;
  if (idx >= DIN * DHID) return;
  {
    int j = idx & 7, lane = (idx >> 3) & 63, ks = (idx >> 9) & 7,
        wid = (idx >> 12) & 7, ch = idx >> 15;
    int n = ch * 128 + wid * 16 + (lane & 15);
    int k = ks * 32 + (lane >> 4) * 8 + j;
    W1p[idx] = f2bf(W1[k * DHID + n]);
  }
  {
    int j = idx & 7, lane = (idx >> 3) & 63, ks = (idx >> 9) & 15,
        nt = (idx >> 13) & 1, wid = idx >> 14;
    int n = wid * 32 + nt * 16 + (lane & 15);
    int k = ks * 32 + (lane >> 4) * 8 + j;
    W2p[idx] = f2bf(W2[k * DIN + n]);
  }
}

// Persistent RK2(midpoint)x2 integrator, transposed state layout (r17/r19
// champion math, byte-identical loops). ONLY change vs r19:
// __launch_bounds__(512, 3) — request 3 waves/EU (cap ~170 total regs).
// Rationale: r19 allocates ~134 total regs/wave (110 arch peak + 24 acc)
// but is scheduled at the 256-reg tier (2 waves/SIMD, 8 waves/CU) because
// the bound only promised 2. If the HW's intermediate tier exists
// (waves/SIMD = floor(512/regs)), this yields 12 waves/CU = +50% latency
// hiding at unchanged pressure. Go/no-go: WRITE_SIZE stays 65 MB (no
// spill) and Occupancy ~34%. If the compiler squeezes/spills instead,
// revert to r19 = the ceiling.
__global__ __launch_bounds__(512, 3)
void ode_all(const float* __restrict__ x, float* __restrict__ out,
             const unsigned short* __restrict__ W1p, const unsigned short* __restrict__ W2p,
             const float* __restrict__ b1, const float* __restrict__ b2)
{
  __shared__ unsigned short Ash[BM * APAD];    // 16.9 KB
  __shared__ unsigned short Hsh[BM * HPADW];   // 33.3 KB (total 50 KB)

  const int tid  = threadIdx.x;
  const int lane = tid & 63;
  const int wid  = tid >> 6;     // 0..7
  const int l15  = lane & 15;
  const int l4   = lane >> 4;    // 0..3
  const size_t r0 = (size_t)blockIdx.x * BM;

  // b2 for this thread's 2x4 output cols: col = wid*32 + nt*16 + l4*4 + r
  f32x4 b2v[2];
  #pragma unroll
  for (int nt = 0; nt < 2; ++nt)
    b2v[nt] = *reinterpret_cast<const f32x4*>(b2 + wid * 32 + nt * 16 + l4 * 4);

  // y^T[col][b]: y[rtB][nt], b = rtB*16 + l15, col = wid*32 + nt*16 + l4*4 + r
  f32x4 y[2][2];
  #pragma unroll
  for (int rtB = 0; rtB < 2; ++rtB)
    #pragma unroll
    for (int nt = 0; nt < 2; ++nt)
      y[rtB][nt] = *reinterpret_cast<const f32x4*>(
          x + (r0 + rtB * 16 + l15) * DIN + wid * 32 + nt * 16 + l4 * 4);

  const float h = 1.0f / (float)NSTEPS;

  const unsigned short* w2b0 = W2p + ((size_t)(wid * 2 + 0) * 16) * 512 + (lane << 3);
  const unsigned short* w2b1 = W2p + ((size_t)(wid * 2 + 1) * 16) * 512 + (lane << 3);

  // ---- prologue: stage X_0 = y into Ash (packed cvt_pk + b64 write) ----
  #pragma unroll
  for (int rtB = 0; rtB < 2; ++rtB)
    #pragma unroll
    for (int nt = 0; nt < 2; ++nt)
      *reinterpret_cast<u64*>(&Ash[(rtB * 16 + l15) * APAD + wid * 32 + nt * 16 + l4 * 4]) =
          pack4bf(y[rtB][nt][0], y[rtB][nt][1], y[rtB][nt][2], y[rtB][nt][3]);

  #pragma unroll 1
  for (int s = 0; s < NSTEPS; ++s){
    #pragma unroll 1
    for (int st = 0; st < 2; ++st){
      __syncthreads();                                   // BAR1: Ash ready

      // ---- GEMM1 in 4 chunks: U^T = W1ch^T x X^T (acc1 = 8 regs) ----
      #pragma unroll 1
      for (int ch = 0; ch < 4; ++ch){
        f32x4 acc1[2];
        acc1[0] = (f32x4){0.f, 0.f, 0.f, 0.f};
        acc1[1] = (f32x4){0.f, 0.f, 0.f, 0.f};

        const unsigned short* w1c = W1p + ((size_t)(ch * 8 + wid) * 8) * 512 + (lane << 3);

        #pragma unroll
        for (int ks = 0; ks < 8; ++ks){
          short8 bf0 = *reinterpret_cast<const short8*>(&Ash[(     l15) * APAD + ks * 32 + l4 * 8]);
          short8 bf1 = *reinterpret_cast<const short8*>(&Ash[(16 + l15) * APAD + ks * 32 + l4 * 8]);
          short8 wf  = *reinterpret_cast<const short8*>(w1c + (size_t)ks * 512);
          acc1[0] = __builtin_amdgcn_mfma_f32_16x16x32_bf16(wf, bf0, acc1[0], 0, 0, 0);
          acc1[1] = __builtin_amdgcn_mfma_f32_16x16x32_bf16(wf, bf1, acc1[1], 0, 0, 0);
        }

        // bias + tanh -> packed b64 H-writes (wave-private columns)
        {
          f32x4 bq = *reinterpret_cast<const f32x4*>(b1 + ch * 128 + wid * 16 + l4 * 4);
          #pragma unroll
          for (int rtB = 0; rtB < 2; ++rtB){
            float t0 = tanh_fast(acc1[rtB][0] + bq[0]);
            float t1 = tanh_fast(acc1[rtB][1] + bq[1]);
            float t2 = tanh_fast(acc1[rtB][2] + bq[2]);
            float t3 = tanh_fast(acc1[rtB][3] + bq[3]);
            *reinterpret_cast<u64*>(&Hsh[(rtB * 16 + l15) * HPADW + ch * 128 + wid * 16 + l4 * 4]) =
                pack4bf(t0, t1, t2, t3);
          }
        }
      }
      __syncthreads();                                   // BAR2: Hsh ready, Ash free

      // ---- GEMM2: F^T = W2^T x H^T, K = 512 ----
      f32x4 F[2][2];
      #pragma unroll
      for (int rtB = 0; rtB < 2; ++rtB)
        #pragma unroll
        for (int nt = 0; nt < 2; ++nt)
          F[rtB][nt] = (f32x4){0.f, 0.f, 0.f, 0.f};

      #pragma unroll
      for (int ks = 0; ks < 16; ++ks){
        short8 hf0 = *reinterpret_cast<const short8*>(&Hsh[(     l15) * HPADW + ks * 32 + l4 * 8]);
        short8 hf1 = *reinterpret_cast<const short8*>(&Hsh[(16 + l15) * HPADW + ks * 32 + l4 * 8]);
        short8 w0  = *reinterpret_cast<const short8*>(w2b0 + (size_t)ks * 512);
        short8 w1f = *reinterpret_cast<const short8*>(w2b1 + (size_t)ks * 512);
        F[0][0] = __builtin_amdgcn_mfma_f32_16x16x32_bf16(w0,  hf0, F[0][0], 0, 0, 0);
        F[1][0] = __builtin_amdgcn_mfma_f32_16x16x32_bf16(w0,  hf1, F[1][0], 0, 0, 0);
        F[0][1] = __builtin_amdgcn_mfma_f32_16x16x32_bf16(w1f, hf0, F[0][1], 0, 0, 0);
        F[1][1] = __builtin_amdgcn_mfma_f32_16x16x32_bf16(w1f, hf1, F[1][1], 0, 0, 0);
      }

      // ---- RK2 update + tail-stage next X (Ash free since BAR2) ----
      // st0 (k1): X = y + (h/2)k1.  st1 (k2): y += h k2, X = y.
      #pragma unroll
      for (int rtB = 0; rtB < 2; ++rtB)
        #pragma unroll
        for (int nt = 0; nt < 2; ++nt){
          float xn[4];
          #pragma unroll
          for (int r = 0; r < 4; ++r){
            float g = F[rtB][nt][r] + b2v[nt][r];
            if (st == 0){
              xn[r] = fmaf(0.5f * h, g, y[rtB][nt][r]);
            } else {
              y[rtB][nt][r] = fmaf(h, g, y[rtB][nt][r]);
              xn[r] = y[rtB][nt][r];
            }
          }
          *reinterpret_cast<u64*>(&Ash[(rtB * 16 + l15) * APAD + wid * 32 + nt * 16 + l4 * 4]) =
              pack4bf(xn[0], xn[1], xn[2], xn[3]);
        }
    }
  }

  // ---- write final state (float4 stores) ----
  #pragma unroll
  for (int rtB = 0; rtB < 2; ++rtB)
    #pragma unroll
    for (int nt = 0; nt < 2; ++nt)
      *reinterpret_cast<f32x4*>(
          out + (r0 + rtB * 16 + l15) * DIN + wid * 32 + nt * 16 + l4 * 4) = y[rtB][nt];
}

extern "C" void kernel_launch(void* const* d_in, const int* in_sizes, int n_in,
                              void* d_out, int out_size, void* d_ws, size_t ws_size,
                              hipStream_t stream)
{
  const float* x  = (const float*)d_in[0];
  const float* W1 = (const float*)d_in[1];
  const float* b1 = (const float*)d_in[2];
  const float* W2 = (const float*)d_in[3];
  const float* b2 = (const float*)d_in[4];
  float* out = (float*)d_out;

  unsigned short* W1p = (unsigned short*)d_ws;
  unsigned short* W2p = W1p + DIN * DHID;   // 512 KiB total

  prep_pack<<<512, 256, 0, stream>>>(W1, W2, W1p, W2p);
  ode_all<<<BATCH / BM, 512, 0, stream>>>(x, out, W1p, W2p, b1, b2);
}

// Round 21
// 260.313 us; speedup vs baseline: 2.4689x; 2.4689x over previous
//
#include <hip/hip_runtime.h>
#include <hip/hip_bf16.h>

#define BATCH 65536
#define DIN   256
#define DHID  512
#define BM    32
#define APAD  264   // 256+8 shorts; rows 16B-aligned
#define HPADW 520   // 512+8 shorts
#define NSTEPS 2    // RK2 (midpoint) x 2 = 4 f-evals

typedef __attribute__((ext_vector_type(8))) short short8;
typedef __attribute__((ext_vector_type(4))) float f32x4;
typedef unsigned long long u64;

__device__ __forceinline__ unsigned short f2bf(float f){
  union { float f; unsigned u; } v; v.f = f;
  unsigned u = v.u;
  unsigned r = (u + 0x7FFFu + ((u >> 16) & 1u)) >> 16;   // RN-even
  return (unsigned short)r;
}
// 4x f32 -> packed 4x bf16 via hardware v_cvt_pk_bf16_f32 (RN-even)
__device__ __forceinline__ u64 pack4bf(float a, float b, float c, float d){
  union { __hip_bfloat162 h2; unsigned u; } lo, hi;
  lo.h2 = __float22bfloat162_rn(make_float2(a, b));
  hi.h2 = __float22bfloat162_rn(make_float2(c, d));
  return (u64)lo.u | ((u64)hi.u << 32);
}
__device__ __forceinline__ float tanh_fast(float x){
  float e = __expf(2.0f * x);
  return 1.0f - 2.0f / (e + 1.0f);
}

// Packed per-wave MFMA fragment order (r10; bytes unchanged, used as the
// A-operand of the swapped mfma — A/B fragment index maps are identical).
__global__ void prep_pack(const float* __restrict__ W1, const float* __restrict__ W2,
                          unsigned short* __restrict__ W1p, unsigned short* __restrict__ W2p){
  int idx = blockIdx.x * blockDim.x + threadIdx.x;
  if (idx >= DIN * DHID) return;
  {
    int j = idx & 7, lane = (idx >> 3) & 63, ks = (idx >> 9) & 7,
        wid = (idx >> 12) & 7, ch = idx >> 15;
    int n = ch * 128 + wid * 16 + (lane & 15);
    int k = ks * 32 + (lane >> 4) * 8 + j;
    W1p[idx] = f2bf(W1[k * DHID + n]);
  }
  {
    int j = idx & 7, lane = (idx >> 3) & 63, ks = (idx >> 9) & 15,
        nt = (idx >> 13) & 1, wid = idx >> 14;
    int n = wid * 32 + nt * 16 + (lane & 15);
    int k = ks * 32 + (lane >> 4) * 8 + j;
    W2p[idx] = f2bf(W2[k * DIN + n]);
  }
}

// Persistent RK2(midpoint)x2 integrator, transposed state layout — the
// session champion (r17/r19: 260 µs graph, 291 µs dispatch, absmax
// 0.06640625 vs threshold 0.136).
// The operating envelope, mapped by rounds 2-20:
//  - (512,2) -> 128 arch VGPR, zero spill, 8 waves/CU: the ONLY spill-free
//    point. (512,1)->128; (512,3)->84+spill; (512,4)->64+spill;
//    (1024,*)->64+spill. Any state beyond ~110 live regs -> GB-scale
//    scratch traffic (r6: 14 GB; r13: 0.5 GB; r18: 0.1 GB — graded by
//    overflow size).
//  - Transposed MFMA (mfma(W,X,C) -> C=[feature][batch]) makes staging
//    writes packed b64 and global I/O float4 (r15: killed the Ash
//    write-allocate traffic).
//  - Fragment-packed weights: every weight load = base + lane*16B, one
//    1KB coalesced transaction (r10: fixed the 16-line-gather TA bottleneck).
//  - NSTEPS=2 by MEASURED h^2 error scaling (h=1/3: +0.001-0.008 over the
//    0.03125 bf16 floor; h=1/2: 0.0664). h=1 would be ~0.14 > 0.136.
__global__ __launch_bounds__(512, 2)
void ode_all(const float* __restrict__ x, float* __restrict__ out,
             const unsigned short* __restrict__ W1p, const unsigned short* __restrict__ W2p,
             const float* __restrict__ b1, const float* __restrict__ b2)
{
  __shared__ unsigned short Ash[BM * APAD];    // 16.9 KB
  __shared__ unsigned short Hsh[BM * HPADW];   // 33.3 KB (total 50 KB)

  const int tid  = threadIdx.x;
  const int lane = tid & 63;
  const int wid  = tid >> 6;     // 0..7
  const int l15  = lane & 15;
  const int l4   = lane >> 4;    // 0..3
  const size_t r0 = (size_t)blockIdx.x * BM;

  // b2 for this thread's 2x4 output cols: col = wid*32 + nt*16 + l4*4 + r
  f32x4 b2v[2];
  #pragma unroll
  for (int nt = 0; nt < 2; ++nt)
    b2v[nt] = *reinterpret_cast<const f32x4*>(b2 + wid * 32 + nt * 16 + l4 * 4);

  // y^T[col][b]: y[rtB][nt], b = rtB*16 + l15, col = wid*32 + nt*16 + l4*4 + r
  f32x4 y[2][2];
  #pragma unroll
  for (int rtB = 0; rtB < 2; ++rtB)
    #pragma unroll
    for (int nt = 0; nt < 2; ++nt)
      y[rtB][nt] = *reinterpret_cast<const f32x4*>(
          x + (r0 + rtB * 16 + l15) * DIN + wid * 32 + nt * 16 + l4 * 4);

  const float h = 1.0f / (float)NSTEPS;

  const unsigned short* w2b0 = W2p + ((size_t)(wid * 2 + 0) * 16) * 512 + (lane << 3);
  const unsigned short* w2b1 = W2p + ((size_t)(wid * 2 + 1) * 16) * 512 + (lane << 3);

  // ---- prologue: stage X_0 = y into Ash (packed cvt_pk + b64 write) ----
  #pragma unroll
  for (int rtB = 0; rtB < 2; ++rtB)
    #pragma unroll
    for (int nt = 0; nt < 2; ++nt)
      *reinterpret_cast<u64*>(&Ash[(rtB * 16 + l15) * APAD + wid * 32 + nt * 16 + l4 * 4]) =
          pack4bf(y[rtB][nt][0], y[rtB][nt][1], y[rtB][nt][2], y[rtB][nt][3]);

  #pragma unroll 1
  for (int s = 0; s < NSTEPS; ++s){
    #pragma unroll 1
    for (int st = 0; st < 2; ++st){
      __syncthreads();                                   // BAR1: Ash ready

      // ---- GEMM1 in 4 chunks: U^T = W1ch^T x X^T (acc1 = 8 regs) ----
      #pragma unroll 1
      for (int ch = 0; ch < 4; ++ch){
        f32x4 acc1[2];
        acc1[0] = (f32x4){0.f, 0.f, 0.f, 0.f};
        acc1[1] = (f32x4){0.f, 0.f, 0.f, 0.f};

        const unsigned short* w1c = W1p + ((size_t)(ch * 8 + wid) * 8) * 512 + (lane << 3);

        #pragma unroll
        for (int ks = 0; ks < 8; ++ks){
          short8 bf0 = *reinterpret_cast<const short8*>(&Ash[(     l15) * APAD + ks * 32 + l4 * 8]);
          short8 bf1 = *reinterpret_cast<const short8*>(&Ash[(16 + l15) * APAD + ks * 32 + l4 * 8]);
          short8 wf  = *reinterpret_cast<const short8*>(w1c + (size_t)ks * 512);
          acc1[0] = __builtin_amdgcn_mfma_f32_16x16x32_bf16(wf, bf0, acc1[0], 0, 0, 0);
          acc1[1] = __builtin_amdgcn_mfma_f32_16x16x32_bf16(wf, bf1, acc1[1], 0, 0, 0);
        }

        // bias + tanh -> packed b64 H-writes (wave-private columns)
        {
          f32x4 bq = *reinterpret_cast<const f32x4*>(b1 + ch * 128 + wid * 16 + l4 * 4);
          #pragma unroll
          for (int rtB = 0; rtB < 2; ++rtB){
            float t0 = tanh_fast(acc1[rtB][0] + bq[0]);
            float t1 = tanh_fast(acc1[rtB][1] + bq[1]);
            float t2 = tanh_fast(acc1[rtB][2] + bq[2]);
            float t3 = tanh_fast(acc1[rtB][3] + bq[3]);
            *reinterpret_cast<u64*>(&Hsh[(rtB * 16 + l15) * HPADW + ch * 128 + wid * 16 + l4 * 4]) =
                pack4bf(t0, t1, t2, t3);
          }
        }
      }
      __syncthreads();                                   // BAR2: Hsh ready, Ash free

      // ---- GEMM2: F^T = W2^T x H^T, K = 512 ----
      f32x4 F[2][2];
      #pragma unroll
      for (int rtB = 0; rtB < 2; ++rtB)
        #pragma unroll
        for (int nt = 0; nt < 2; ++nt)
          F[rtB][nt] = (f32x4){0.f, 0.f, 0.f, 0.f};

      #pragma unroll
      for (int ks = 0; ks < 16; ++ks){
        short8 hf0 = *reinterpret_cast<const short8*>(&Hsh[(     l15) * HPADW + ks * 32 + l4 * 8]);
        short8 hf1 = *reinterpret_cast<const short8*>(&Hsh[(16 + l15) * HPADW + ks * 32 + l4 * 8]);
        short8 w0  = *reinterpret_cast<const short8*>(w2b0 + (size_t)ks * 512);
        short8 w1f = *reinterpret_cast<const short8*>(w2b1 + (size_t)ks * 512);
        F[0][0] = __builtin_amdgcn_mfma_f32_16x16x32_bf16(w0,  hf0, F[0][0], 0, 0, 0);
        F[1][0] = __builtin_amdgcn_mfma_f32_16x16x32_bf16(w0,  hf1, F[1][0], 0, 0, 0);
        F[0][1] = __builtin_amdgcn_mfma_f32_16x16x32_bf16(w1f, hf0, F[0][1], 0, 0, 0);
        F[1][1] = __builtin_amdgcn_mfma_f32_16x16x32_bf16(w1f, hf1, F[1][1], 0, 0, 0);
      }

      // ---- RK2 update + tail-stage next X (Ash free since BAR2) ----
      // st0 (k1): X = y + (h/2)k1.  st1 (k2): y += h k2, X = y.
      #pragma unroll
      for (int rtB = 0; rtB < 2; ++rtB)
        #pragma unroll
        for (int nt = 0; nt < 2; ++nt){
          float xn[4];
          #pragma unroll
          for (int r = 0; r < 4; ++r){
            float g = F[rtB][nt][r] + b2v[nt][r];
            if (st == 0){
              xn[r] = fmaf(0.5f * h, g, y[rtB][nt][r]);
            } else {
              y[rtB][nt][r] = fmaf(h, g, y[rtB][nt][r]);
              xn[r] = y[rtB][nt][r];
            }
          }
          *reinterpret_cast<u64*>(&Ash[(rtB * 16 + l15) * APAD + wid * 32 + nt * 16 + l4 * 4]) =
              pack4bf(xn[0], xn[1], xn[2], xn[3]);
        }
    }
  }

  // ---- write final state (float4 stores) ----
  #pragma unroll
  for (int rtB = 0; rtB < 2; ++rtB)
    #pragma unroll
    for (int nt = 0; nt < 2; ++nt)
      *reinterpret_cast<f32x4*>(
          out + (r0 + rtB * 16 + l15) * DIN + wid * 32 + nt * 16 + l4 * 4) = y[rtB][nt];
}

extern "C" void kernel_launch(void* const* d_in, const int* in_sizes, int n_in,
                              void* d_out, int out_size, void* d_ws, size_t ws_size,
                              hipStream_t stream)
{
  const float* x  = (const float*)d_in[0];
  const float* W1 = (const float*)d_in[1];
  const float* b1 = (const float*)d_in[2];
  const float* W2 = (const float*)d_in[3];
  const float* b2 = (const float*)d_in[4];
  float* out = (float*)d_out;

  unsigned short* W1p = (unsigned short*)d_ws;
  unsigned short* W2p = W1p + DIN * DHID;   // 512 KiB total

  prep_pack<<<512, 256, 0, stream>>>(W1, W2, W1p, W2p);
  ode_all<<<BATCH / BM, 512, 0, stream>>>(x, out, W1p, W2p, b1, b2);
}